// Round 12
// baseline (813.404 us; speedup 1.0000x reference)
//
#include <hip/hip_runtime.h>

#define HH 64
#define WW 64
#define HW 4096
#define CC 256
#define BB 4
#define GG 4
#define NPAIR 3

typedef __attribute__((ext_vector_type(8))) short short8;
typedef __attribute__((ext_vector_type(4))) float f32x4;
typedef unsigned short ushort_t;

__device__ inline ushort_t f2bf(float x) {
    unsigned int u = __float_as_uint(x);
    unsigned int r = (u + 0x7fffu + ((u >> 16) & 1u)) >> 16;
    return (ushort_t)r;
}
__device__ inline float bflo(unsigned u) { return __uint_as_float(u << 16); }
__device__ inline float bfhi(unsigned u) { return __uint_as_float(u & 0xffff0000u); }

// ---------------- weight preps ----------------
__global__ void prep_wdef(const float* __restrict__ wd, ushort_t* __restrict__ wmf) {
    int idx = blockIdx.x * 256 + threadIdx.x;  // 9*256*256
    if (idx >= 9 * 256 * 256) return;
    int k = idx >> 16;
    int rem = idx & 65535;
    int o = rem >> 8;
    int c = rem & 255;
    wmf[idx] = f2bf(wd[((size_t)(o * 256 + c)) * 9 + k]);
}

__global__ void prep_woff(const float* __restrict__ wo, ushort_t* __restrict__ wmf) {
    int idx = blockIdx.x * 256 + threadIdx.x;  // 9*80*320
    if (idx >= 9 * 80 * 320) return;
    int k = idx / (80 * 320);
    int rem = idx % (80 * 320);
    int o = rem / 320;
    int ci = rem % 320;
    wmf[idx] = (o < 72 && ci < 305) ? f2bf(wo[((size_t)o * 305 + ci) * 9 + k]) : (ushort_t)0;
}

__global__ void prep_wfus(const float* __restrict__ wf, ushort_t* __restrict__ wmf) {
    int idx = blockIdx.x * 256 + threadIdx.x;  // 9*256*1024
    if (idx >= 9 * 256 * 1024) return;
    int k = idx / (256 * 1024);
    int rem = idx % (256 * 1024);
    int o = rem / 1024;
    int ci = rem % 1024;
    wmf[idx] = f2bf(wf[((size_t)o * 1024 + ci) * 9 + k]);
}

// ---------------- XT build ----------------
__global__ void __launch_bounds__(256) xt_build(const float* __restrict__ in,
                                                ushort_t* __restrict__ XT) {
    __shared__ ushort_t tileT[64][72];
    int hw0 = blockIdx.x * 64;
    int ct = blockIdx.y;
    int z = blockIdx.z;
    int pair = z >> 2, b = z & 3;
    int t = threadIdx.x;
    int cil = t >> 2, q = t & 3;
    const float* sp = in + ((size_t)(b * 4 + pair) * 256 + ct * 64 + cil) * HW + hw0 + q * 16;
#pragma unroll
    for (int i = 0; i < 16; ++i) tileT[q * 16 + i][cil] = f2bf(sp[i]);
    __syncthreads();
    int hwl = t >> 2;
    const uint4* tp = reinterpret_cast<const uint4*>(&tileT[hwl][q * 16]);
    uint4* op = reinterpret_cast<uint4*>(
        &XT[((size_t)z * HW + hw0 + hwl) * 320 + ct * 64 + q * 16]);
    op[0] = tp[0];
    op[1] = tp[1];
}

// ---------------- correlation partials ----------------
__global__ void __launch_bounds__(256, 8) corr_partial(const float* __restrict__ in,
                                                       float* __restrict__ P) {
    __shared__ float x1l[8][64];
    __shared__ float x2l[8][7][76];
    int h = blockIdx.x, z = blockIdx.y, cg = blockIdx.z;
    int pair = z >> 2, b = z & 3;
    const float* x1 = in + (size_t)(b * GG + pair) * CC * HW + h * WW;
    const float* x2 = in + (size_t)(b * GG + 3) * CC * HW;
    int tid = threadIdx.x;
    int w = tid & 63;
    int dg = tid >> 6;

    float acc[2][7];
#pragma unroll
    for (int i = 0; i < 2; ++i)
#pragma unroll
        for (int j = 0; j < 7; ++j) acc[i][j] = 0.f;

    for (int c0 = cg * 64; c0 < cg * 64 + 64; c0 += 8) {
        __syncthreads();
#pragma unroll
        for (int idx = tid; idx < 512; idx += 256) {
            int cc = idx >> 6, ww = idx & 63;
            x1l[cc][ww] = x1[(size_t)(c0 + cc) * HW + ww];
        }
        for (int idx = tid; idx < 8 * 7 * 76; idx += 256) {
            int cc = idx / 532;
            int rem = idx - cc * 532;
            int r = rem / 76;
            int cl = rem - r * 76;
            int row = h + 2 * (r - 3);
            int col = cl - 6;
            float v = 0.f;
            if (row >= 0 && row < HH && col >= 0 && col < WW)
                v = x2[(size_t)(c0 + cc) * HW + row * WW + col];
            x2l[cc][r][cl] = v;
        }
        __syncthreads();
#pragma unroll
        for (int cc = 0; cc < 8; ++cc) {
            float x1v = x1l[cc][w];
#pragma unroll
            for (int i = 0; i < 2; ++i) {
                int di = dg * 2 + i;
                if (di < 7) {
#pragma unroll
                    for (int dj = 0; dj < 7; ++dj)
                        acc[i][dj] += x1v * x2l[cc][di][w + 2 * dj];
                }
            }
        }
    }
    float* pp = P + ((size_t)(cg * 12 + z) * 49) * HW + h * WW + w;
#pragma unroll
    for (int i = 0; i < 2; ++i) {
        int di = dg * 2 + i;
        if (di < 7) {
#pragma unroll
            for (int dj = 0; dj < 7; ++dj)
                pp[(size_t)(di * 7 + dj) * HW] = acc[i][dj];
        }
    }
}

// ---------------- corr reduce ----------------
__global__ void __launch_bounds__(256) corr_reduce(const float* __restrict__ P,
                                                   ushort_t* __restrict__ XT) {
    int h = blockIdx.x, z = blockIdx.y;
    int tid = threadIdx.x;
    int w = tid & 63;
    int dg = tid >> 6;
    const size_t cgs = (size_t)12 * 49 * HW;
    ushort_t* xrow = XT + ((size_t)z * HW + h * WW + w) * 320;
#pragma unroll
    for (int i = 0; i < 2; ++i) {
        int di = dg * 2 + i;
        if (di < 7) {
#pragma unroll
            for (int dj = 0; dj < 7; ++dj) {
                int d = di * 7 + dj;
                const float* pp = P + ((size_t)z * 49 + d) * HW + h * WW + w;
                float s = pp[0] + pp[cgs] + pp[2 * cgs] + pp[3 * cgs];
                xrow[256 + d] = f2bf(s * (1.f / 256.f));
            }
        }
    }
    if (dg == 3) {
#pragma unroll
        for (int p = 0; p < 15; ++p) xrow[305 + p] = 0;
    }
}

// ---------------- offset conv via MFMA bf16 ----------------
__global__ void __launch_bounds__(256, 2) offconv_mfma(const ushort_t* __restrict__ XT,
                                                       const ushort_t* __restrict__ wmf,
                                                       float* __restrict__ off) {
    __shared__ ushort_t a_lds[80][40];
    __shared__ ushort_t b_lds[128][40];
    int n0 = blockIdx.x * 128;
    int z = blockIdx.y;
    int t = threadIdx.x;
    int wid = t >> 6;
    int lane = t & 63;
    int l15 = lane & 15;
    int kq = lane >> 4;
    int r2 = t >> 1, half = t & 1;
    int hwB = n0 + r2;
    int hB = hwB >> 6, wB = hwB & 63;
    const ushort_t* xtb = XT + (size_t)z * HW * 320;

    f32x4 acc[5][2];
#pragma unroll
    for (int m = 0; m < 5; ++m)
#pragma unroll
        for (int n = 0; n < 2; ++n) acc[m][n] = (f32x4){0.f, 0.f, 0.f, 0.f};

    for (int tap = 0; tap < 9; ++tap) {
        int kh = tap / 3;
        int kw = tap - kh * 3;
        int hP = hB + kh - 1;
        int wP = wB + kw - 1;
        bool valid = (hP >= 0) && (hP < HH) && (wP >= 0) && (wP < WW);
        const ushort_t* brow = xtb + (size_t)(hP * WW + wP) * 320;
#pragma unroll 1
        for (int cs = 0; cs < 10; ++cs) {
            int ci0 = cs * 32;
            uint4 vb0 = make_uint4(0, 0, 0, 0), vb1 = make_uint4(0, 0, 0, 0);
            if (valid) {
                const uint4* gp = reinterpret_cast<const uint4*>(brow + ci0 + half * 16);
                vb0 = gp[0];
                vb1 = gp[1];
            }
            uint4 va0, va1;
            if (t < 160) {
                const uint4* ga = reinterpret_cast<const uint4*>(
                    wmf + ((size_t)tap * 80 + r2) * 320 + ci0 + half * 16);
                va0 = ga[0];
                va1 = ga[1];
            }
            __syncthreads();
            {
                uint4* bp = reinterpret_cast<uint4*>(&b_lds[r2][half * 16]);
                bp[0] = vb0;
                bp[1] = vb1;
                if (t < 160) {
                    uint4* ap = reinterpret_cast<uint4*>(&a_lds[r2][half * 16]);
                    ap[0] = va0;
                    ap[1] = va1;
                }
            }
            __syncthreads();
            short8 af[5], bf[2];
#pragma unroll
            for (int m = 0; m < 5; ++m)
                af[m] = *reinterpret_cast<const short8*>(&a_lds[m * 16 + l15][kq * 8]);
#pragma unroll
            for (int n = 0; n < 2; ++n)
                bf[n] = *reinterpret_cast<const short8*>(&b_lds[wid * 32 + n * 16 + l15][kq * 8]);
#pragma unroll
            for (int m = 0; m < 5; ++m)
#pragma unroll
                for (int n = 0; n < 2; ++n)
                    acc[m][n] = __builtin_amdgcn_mfma_f32_16x16x32_bf16(af[m], bf[n],
                                                                        acc[m][n], 0, 0, 0);
        }
    }
    float* ob = off + (size_t)z * 72 * HW + n0 + wid * 32;
#pragma unroll
    for (int m = 0; m < 5; ++m)
#pragma unroll
        for (int n = 0; n < 2; ++n)
#pragma unroll
            for (int e = 0; e < 4; ++e) {
                int o_l = m * 16 + kq * 4 + e;
                if (o_l < 72) ob[(size_t)o_l * HW + n * 16 + l15] = acc[m][n][e];
            }
}

// ---------------- deformable conv via MFMA bf16 (coalesced quadrant sampling) ----------------
// r10 geometry: grid 768 XCD-chunked, block (z,h), 4 waves x (64o x 64w), 4x4 frags.
// NEW sampling: per (g,w) task, lane = (quadrant q = lane>>4, ch-pair cp = lane&15):
// each 16-lane group loads one bilinear neighbor's 64B contiguous channel run
// (4 TA transactions/instr vs 64 scattered), scales by quadrant weight, then
// shfl_xor(16)+shfl_xor(32) butterflies sum quadrants in-register; q==0 lanes
// pack bf16x2 and write LDS. Offsets staged per-k into LDS (broadcast reads).
__global__ void __launch_bounds__(256, 3) deform_mfma(const ushort_t* __restrict__ XT,
                                                      const float* __restrict__ off,
                                                      const ushort_t* __restrict__ wmf,
                                                      ushort_t* __restrict__ FT) {
    __shared__ ushort_t b_lds[64][264];
    __shared__ float off_lds[4][2][64];
    int u = blockIdx.x & 7, v = blockIdx.x >> 3;
    int lin = u * 96 + v;
    int z = lin >> 6, h = lin & 63;
    int b = z & 3, pair = z >> 2;

    const ushort_t* xtz = XT + (size_t)z * HW * 320;
    const float* offp = off + (size_t)z * 72 * HW;
    int tid = threadIdx.x;
    int lane = tid & 63;
    int g = tid >> 6;
    int l15 = tid & 15;
    int kq = (tid >> 4) & 3;
    int q = lane >> 4, cp = lane & 15;

    f32x4 acc[4][4];
#pragma unroll
    for (int m = 0; m < 4; ++m)
#pragma unroll
        for (int n = 0; n < 4; ++n) acc[m][n] = (f32x4){0.f, 0.f, 0.f, 0.f};

    for (int k = 0; k < 9; ++k) {
        __syncthreads();
        // ---- stage this tap's offsets: off_lds[g][{oy,ox}][w] ----
        for (int idx = tid; idx < 512; idx += 256)
            off_lds[idx >> 7][(idx >> 6) & 1][idx & 63] =
                offp[(size_t)((idx >> 7) * 18 + k * 2 + ((idx >> 6) & 1)) * HW +
                     h * WW + (idx & 63)];
        __syncthreads();
        float fk_h = (float)(k / 3 - 1), fk_w = (float)(k % 3 - 1);
        // ---- sampling: wave g, 64 tasks (w), coalesced quadrant loads ----
#pragma unroll 2
        for (int w = 0; w < 64; ++w) {
            float oy = off_lds[g][0][w];
            float ox = off_lds[g][1][w];
            float py = (float)h + fk_h + oy;
            float px = (float)w + fk_w + ox;
            float y0f = floorf(py), x0f = floorf(px);
            float fy = py - y0f, fx = px - x0f;
            int yq = (int)y0f + (q >> 1);
            int xq = (int)x0f + (q & 1);
            bool vld = (yq >= 0) && (yq < HH) && (xq >= 0) && (xq < WW);
            float wy = (q & 2) ? fy : 1.f - fy;
            float wx = (q & 1) ? fx : 1.f - fx;
            float wq = wy * wx * (vld ? 1.f : 0.f);
            int cy = min(max(yq, 0), HH - 1), cx = min(max(xq, 0), WW - 1);
            const ushort_t* pb = xtz + (size_t)(cy * WW + cx) * 320 + g * 64;
#pragma unroll
            for (int half = 0; half < 2; ++half) {
                unsigned uv = *reinterpret_cast<const unsigned*>(pb + half * 32 + cp * 2);
                float s0 = wq * bflo(uv);
                float s1 = wq * bfhi(uv);
                s0 += __shfl_xor(s0, 16);
                s1 += __shfl_xor(s1, 16);
                s0 += __shfl_xor(s0, 32);
                s1 += __shfl_xor(s1, 32);
                if (q == 0) {
                    unsigned pwv = (unsigned)f2bf(s0) | ((unsigned)f2bf(s1) << 16);
                    *reinterpret_cast<unsigned*>(
                        &b_lds[w][g * 64 + half * 32 + cp * 2]) = pwv;
                }
            }
        }
        __syncthreads();
        // ---- MFMA: wave g owns o-range g*64..+63, all 64 w (r10 verbatim) ----
        const ushort_t* wkbase = wmf + (size_t)k * 65536 + (size_t)(g * 64) * 256;
#pragma unroll 1
        for (int cs = 0; cs < 8; ++cs) {
            int c0 = cs * 32;
            short8 bfr[4], afr[4];
#pragma unroll
            for (int n = 0; n < 4; ++n)
                bfr[n] = *reinterpret_cast<const short8*>(&b_lds[n * 16 + l15][c0 + kq * 8]);
#pragma unroll
            for (int m = 0; m < 4; ++m)
                afr[m] = *reinterpret_cast<const short8*>(
                    wkbase + (size_t)(m * 16 + l15) * 256 + c0 + kq * 8);
#pragma unroll
            for (int m = 0; m < 4; ++m)
#pragma unroll
                for (int n = 0; n < 4; ++n)
                    acc[m][n] = __builtin_amdgcn_mfma_f32_16x16x32_bf16(afr[m], bfr[n],
                                                                        acc[m][n], 0, 0, 0);
        }
    }
    // ---- epilogue (r10 verbatim): transpose via LDS, write bf16 into FT ----
    __syncthreads();
#pragma unroll
    for (int m = 0; m < 4; ++m)
#pragma unroll
        for (int n = 0; n < 4; ++n) {
            unsigned lo = (unsigned)f2bf(acc[m][n][0]) | ((unsigned)f2bf(acc[m][n][1]) << 16);
            unsigned hi = (unsigned)f2bf(acc[m][n][2]) | ((unsigned)f2bf(acc[m][n][3]) << 16);
            uint2 vv = make_uint2(lo, hi);
            *reinterpret_cast<uint2*>(&b_lds[n * 16 + l15][g * 64 + m * 16 + kq * 4]) = vv;
        }
    __syncthreads();
    int wout = tid >> 2, ch = tid & 3;
    ushort_t* dst = FT + ((size_t)b * HW + h * 64 + wout) * 1024 + pair * 256 + ch * 64;
    const ushort_t* srcl = &b_lds[wout][ch * 64];
#pragma unroll
    for (int i = 0; i < 8; ++i) {
        uint4 vv = *reinterpret_cast<const uint4*>(srcl + i * 8);
        *reinterpret_cast<uint4*>(dst + i * 8) = vv;
    }
}

// ---------------- FT build (y part) ----------------
__global__ void __launch_bounds__(256) ft_build_y(const float* __restrict__ in,
                                                  ushort_t* __restrict__ FT) {
    __shared__ ushort_t tileT[64][72];
    int hw0 = blockIdx.x * 64;
    int ct = blockIdx.y;
    int b = blockIdx.z;
    int t = threadIdx.x;
    int cil = t >> 2, q = t & 3;
    const float* sp = in + ((size_t)(b * 4 + 3) * 256 + ct * 64 + cil) * HW + hw0 + q * 16;
#pragma unroll
    for (int i = 0; i < 16; ++i) tileT[q * 16 + i][cil] = f2bf(sp[i]);
    __syncthreads();
    int hwl = t >> 2;
    const uint4* tp = reinterpret_cast<const uint4*>(&tileT[hwl][q * 16]);
    uint4* op = reinterpret_cast<uint4*>(
        &FT[((size_t)b * HW + hw0 + hwl) * 1024 + 768 + ct * 64 + q * 16]);
    op[0] = tp[0];
    op[1] = tp[1];
}

// ---------------- fusion conv via MFMA bf16 (halo-staged B, XCD-chunked) ----------------
__global__ void __launch_bounds__(256, 2) fusion_mfma(const ushort_t* __restrict__ FT,
                                                      const ushort_t* __restrict__ wmf,
                                                      float* __restrict__ out) {
    __shared__ ushort_t a_lds[9][64][32];
    __shared__ ushort_t b_hal[264][32];
    int lin = ((blockIdx.x & 7) << 6) | (blockIdx.x >> 3);
    int ot = lin & 3;
    int g2 = lin >> 2;
    int n0t = g2 & 31;
    int b = g2 >> 5;
    int o0 = ot * 64;
    int h0 = n0t * 2;
    int t = threadIdx.x;
    int wid = t >> 6;
    int lane = t & 63;
    int l15 = lane & 15;
    int kq = lane >> 4;
    const ushort_t* ftb = FT + (size_t)b * HW * 1024;

    f32x4 acc[4][2];
#pragma unroll
    for (int fm = 0; fm < 4; ++fm)
#pragma unroll
        for (int fn = 0; fn < 2; ++fn) acc[fm][fn] = (f32x4){0.f, 0.f, 0.f, 0.f};

#pragma unroll 1
    for (int cs = 0; cs < 32; ++cs) {
        int ci0 = cs * 32;
        __syncthreads();
        for (int idx = t; idx < 264; idx += 256) {
            int r = idx / 66, c = idx - r * 66;
            int hP = h0 + r - 1, wP = c - 1;
            uint4* dst = reinterpret_cast<uint4*>(&b_hal[idx][0]);
            if (hP >= 0 && hP < HH && wP >= 0 && wP < WW) {
                const uint4* src = reinterpret_cast<const uint4*>(
                    ftb + (size_t)(hP * WW + wP) * 1024 + ci0);
                dst[0] = src[0];
                dst[1] = src[1];
                dst[2] = src[2];
                dst[3] = src[3];
            } else {
                uint4 zz = make_uint4(0, 0, 0, 0);
                dst[0] = zz;
                dst[1] = zz;
                dst[2] = zz;
                dst[3] = zz;
            }
        }
        for (int idx = t; idx < 2304; idx += 256) {
            int tp = idx >> 8;
            int rem = idx & 255;
            int o = rem >> 2, q = rem & 3;
            *reinterpret_cast<uint4*>(&a_lds[tp][o][q * 8]) =
                *reinterpret_cast<const uint4*>(
                    wmf + ((size_t)(tp * 256 + o0 + o) << 10) + ci0 + q * 8);
        }
        __syncthreads();
#pragma unroll 1
        for (int tap = 0; tap < 9; ++tap) {
            int kh = tap / 3, kw = tap - kh * 3;
            short8 af[4], bf[2];
#pragma unroll
            for (int m = 0; m < 4; ++m)
                af[m] = *reinterpret_cast<const short8*>(&a_lds[tap][m * 16 + l15][kq * 8]);
#pragma unroll
            for (int n = 0; n < 2; ++n) {
                int p = wid * 32 + n * 16 + l15;
                int pos = ((p >> 6) + kh) * 66 + (p & 63) + kw;
                bf[n] = *reinterpret_cast<const short8*>(&b_hal[pos][kq * 8]);
            }
#pragma unroll
            for (int m = 0; m < 4; ++m)
#pragma unroll
                for (int n = 0; n < 2; ++n)
                    acc[m][n] = __builtin_amdgcn_mfma_f32_16x16x32_bf16(af[m], bf[n],
                                                                        acc[m][n], 0, 0, 0);
        }
    }
    float* ob = out + ((size_t)b * 256 + o0) * HW + h0 * 64 + wid * 32;
#pragma unroll
    for (int fm = 0; fm < 4; ++fm)
#pragma unroll
        for (int fn = 0; fn < 2; ++fn)
#pragma unroll
            for (int e = 0; e < 4; ++e) {
                int o_l = fm * 16 + 4 * kq + e;
                ob[(size_t)o_l * HW + fn * 16 + l15] = acc[fm][fn][e];
            }
}

extern "C" void kernel_launch(void* const* d_in, const int* in_sizes, int n_in,
                              void* d_out, int out_size, void* d_ws, size_t ws_size,
                              hipStream_t stream) {
    const float* in   = (const float*)d_in[0];   // [16,256,64,64]
    const float* wOff = (const float*)d_in[1];   // [72,305,3,3]
    const float* wDef = (const float*)d_in[2];   // [256,256,3,3]
    const float* wFus = (const float*)d_in[3];   // [256,1024,3,3]
    float* out = (float*)d_out;                  // [4,256,64,64]
    char* base = (char*)d_ws;

    ushort_t* XT     = (ushort_t*)base;                 // 31,457,280 B
    ushort_t* FT     = (ushort_t*)(base + 31457280);    // 33,554,432 B -> 65,011,712
    float* corrP     = (float*)(base + 31457280);       // 38,535,168 B (dead early)
    float* offB      = (float*)(base + 65011712);       // 14,155,776 B -> 79,167,488
    ushort_t* wdefMF = (ushort_t*)(base + 79167488);    //  1,179,648 B -> 80,347,136
    ushort_t* woffMF = (ushort_t*)(base + 80347136);    //    460,800 B -> 80,807,936
    ushort_t* wfusMF = (ushort_t*)(base + 80807936);    //  4,718,592 B -> 85,526,528

    hipLaunchKernelGGL(prep_wdef, dim3((9 * 256 * 256 + 255) / 256), dim3(256), 0, stream,
                       wDef, wdefMF);
    hipLaunchKernelGGL(prep_woff, dim3((9 * 80 * 320 + 255) / 256), dim3(256), 0, stream,
                       wOff, woffMF);
    hipLaunchKernelGGL(prep_wfus, dim3((9 * 256 * 1024 + 255) / 256), dim3(256), 0, stream,
                       wFus, wfusMF);
    hipLaunchKernelGGL(xt_build, dim3(64, 4, 12), dim3(256), 0, stream, in, XT);
    hipLaunchKernelGGL(corr_partial, dim3(64, 12, 4), dim3(256), 0, stream, in, corrP);
    hipLaunchKernelGGL(corr_reduce, dim3(64, 12), dim3(256), 0, stream, corrP, XT);
    hipLaunchKernelGGL(offconv_mfma, dim3(32, 12), dim3(256), 0, stream, XT, woffMF, offB);
    hipLaunchKernelGGL(ft_build_y, dim3(64, 4, 4), dim3(256), 0, stream, in, FT);
    hipLaunchKernelGGL(deform_mfma, dim3(768), dim3(256), 0, stream, XT, offB, wdefMF, FT);
    hipLaunchKernelGGL(fusion_mfma, dim3(512), dim3(256), 0, stream, FT, wfusMF, out);
}

// Round 13
// 597.770 us; speedup vs baseline: 1.3607x; 1.3607x over previous
//
#include <hip/hip_runtime.h>

#define HH 64
#define WW 64
#define HW 4096
#define CC 256
#define BB 4
#define GG 4
#define NPAIR 3

typedef __attribute__((ext_vector_type(8))) short short8;
typedef __attribute__((ext_vector_type(4))) float f32x4;
typedef unsigned short ushort_t;

__device__ inline ushort_t f2bf(float x) {
    unsigned int u = __float_as_uint(x);
    unsigned int r = (u + 0x7fffu + ((u >> 16) & 1u)) >> 16;
    return (ushort_t)r;
}
__device__ inline float bflo(unsigned u) { return __uint_as_float(u << 16); }
__device__ inline float bfhi(unsigned u) { return __uint_as_float(u & 0xffff0000u); }

// ---------------- weight preps ----------------
__global__ void prep_wdef(const float* __restrict__ wd, ushort_t* __restrict__ wmf) {
    int idx = blockIdx.x * 256 + threadIdx.x;  // 9*256*256
    if (idx >= 9 * 256 * 256) return;
    int k = idx >> 16;
    int rem = idx & 65535;
    int o = rem >> 8;
    int c = rem & 255;
    wmf[idx] = f2bf(wd[((size_t)(o * 256 + c)) * 9 + k]);
}

__global__ void prep_woff(const float* __restrict__ wo, ushort_t* __restrict__ wmf) {
    int idx = blockIdx.x * 256 + threadIdx.x;  // 9*80*320
    if (idx >= 9 * 80 * 320) return;
    int k = idx / (80 * 320);
    int rem = idx % (80 * 320);
    int o = rem / 320;
    int ci = rem % 320;
    wmf[idx] = (o < 72 && ci < 305) ? f2bf(wo[((size_t)o * 305 + ci) * 9 + k]) : (ushort_t)0;
}

__global__ void prep_wfus(const float* __restrict__ wf, ushort_t* __restrict__ wmf) {
    int idx = blockIdx.x * 256 + threadIdx.x;  // 9*256*1024
    if (idx >= 9 * 256 * 1024) return;
    int k = idx / (256 * 1024);
    int rem = idx % (256 * 1024);
    int o = rem / 1024;
    int ci = rem % 1024;
    wmf[idx] = f2bf(wf[((size_t)o * 1024 + ci) * 9 + k]);
}

// ---------------- XT build ----------------
__global__ void __launch_bounds__(256) xt_build(const float* __restrict__ in,
                                                ushort_t* __restrict__ XT) {
    __shared__ ushort_t tileT[64][72];
    int hw0 = blockIdx.x * 64;
    int ct = blockIdx.y;
    int z = blockIdx.z;
    int pair = z >> 2, b = z & 3;
    int t = threadIdx.x;
    int cil = t >> 2, q = t & 3;
    const float* sp = in + ((size_t)(b * 4 + pair) * 256 + ct * 64 + cil) * HW + hw0 + q * 16;
#pragma unroll
    for (int i = 0; i < 16; ++i) tileT[q * 16 + i][cil] = f2bf(sp[i]);
    __syncthreads();
    int hwl = t >> 2;
    const uint4* tp = reinterpret_cast<const uint4*>(&tileT[hwl][q * 16]);
    uint4* op = reinterpret_cast<uint4*>(
        &XT[((size_t)z * HW + hw0 + hwl) * 320 + ct * 64 + q * 16]);
    op[0] = tp[0];
    op[1] = tp[1];
}

// ---------------- correlation partials ----------------
__global__ void __launch_bounds__(256, 8) corr_partial(const float* __restrict__ in,
                                                       float* __restrict__ P) {
    __shared__ float x1l[8][64];
    __shared__ float x2l[8][7][76];
    int h = blockIdx.x, z = blockIdx.y, cg = blockIdx.z;
    int pair = z >> 2, b = z & 3;
    const float* x1 = in + (size_t)(b * GG + pair) * CC * HW + h * WW;
    const float* x2 = in + (size_t)(b * GG + 3) * CC * HW;
    int tid = threadIdx.x;
    int w = tid & 63;
    int dg = tid >> 6;

    float acc[2][7];
#pragma unroll
    for (int i = 0; i < 2; ++i)
#pragma unroll
        for (int j = 0; j < 7; ++j) acc[i][j] = 0.f;

    for (int c0 = cg * 64; c0 < cg * 64 + 64; c0 += 8) {
        __syncthreads();
#pragma unroll
        for (int idx = tid; idx < 512; idx += 256) {
            int cc = idx >> 6, ww = idx & 63;
            x1l[cc][ww] = x1[(size_t)(c0 + cc) * HW + ww];
        }
        for (int idx = tid; idx < 8 * 7 * 76; idx += 256) {
            int cc = idx / 532;
            int rem = idx - cc * 532;
            int r = rem / 76;
            int cl = rem - r * 76;
            int row = h + 2 * (r - 3);
            int col = cl - 6;
            float v = 0.f;
            if (row >= 0 && row < HH && col >= 0 && col < WW)
                v = x2[(size_t)(c0 + cc) * HW + row * WW + col];
            x2l[cc][r][cl] = v;
        }
        __syncthreads();
#pragma unroll
        for (int cc = 0; cc < 8; ++cc) {
            float x1v = x1l[cc][w];
#pragma unroll
            for (int i = 0; i < 2; ++i) {
                int di = dg * 2 + i;
                if (di < 7) {
#pragma unroll
                    for (int dj = 0; dj < 7; ++dj)
                        acc[i][dj] += x1v * x2l[cc][di][w + 2 * dj];
                }
            }
        }
    }
    float* pp = P + ((size_t)(cg * 12 + z) * 49) * HW + h * WW + w;
#pragma unroll
    for (int i = 0; i < 2; ++i) {
        int di = dg * 2 + i;
        if (di < 7) {
#pragma unroll
            for (int dj = 0; dj < 7; ++dj)
                pp[(size_t)(di * 7 + dj) * HW] = acc[i][dj];
        }
    }
}

// ---------------- corr reduce ----------------
__global__ void __launch_bounds__(256) corr_reduce(const float* __restrict__ P,
                                                   ushort_t* __restrict__ XT) {
    int h = blockIdx.x, z = blockIdx.y;
    int tid = threadIdx.x;
    int w = tid & 63;
    int dg = tid >> 6;
    const size_t cgs = (size_t)12 * 49 * HW;
    ushort_t* xrow = XT + ((size_t)z * HW + h * WW + w) * 320;
#pragma unroll
    for (int i = 0; i < 2; ++i) {
        int di = dg * 2 + i;
        if (di < 7) {
#pragma unroll
            for (int dj = 0; dj < 7; ++dj) {
                int d = di * 7 + dj;
                const float* pp = P + ((size_t)z * 49 + d) * HW + h * WW + w;
                float s = pp[0] + pp[cgs] + pp[2 * cgs] + pp[3 * cgs];
                xrow[256 + d] = f2bf(s * (1.f / 256.f));
            }
        }
    }
    if (dg == 3) {
#pragma unroll
        for (int p = 0; p < 15; ++p) xrow[305 + p] = 0;
    }
}

// ---------------- offset conv via MFMA bf16 ----------------
__global__ void __launch_bounds__(256, 2) offconv_mfma(const ushort_t* __restrict__ XT,
                                                       const ushort_t* __restrict__ wmf,
                                                       float* __restrict__ off) {
    __shared__ ushort_t a_lds[80][40];
    __shared__ ushort_t b_lds[128][40];
    int n0 = blockIdx.x * 128;
    int z = blockIdx.y;
    int t = threadIdx.x;
    int wid = t >> 6;
    int lane = t & 63;
    int l15 = lane & 15;
    int kq = lane >> 4;
    int r2 = t >> 1, half = t & 1;
    int hwB = n0 + r2;
    int hB = hwB >> 6, wB = hwB & 63;
    const ushort_t* xtb = XT + (size_t)z * HW * 320;

    f32x4 acc[5][2];
#pragma unroll
    for (int m = 0; m < 5; ++m)
#pragma unroll
        for (int n = 0; n < 2; ++n) acc[m][n] = (f32x4){0.f, 0.f, 0.f, 0.f};

    for (int tap = 0; tap < 9; ++tap) {
        int kh = tap / 3;
        int kw = tap - kh * 3;
        int hP = hB + kh - 1;
        int wP = wB + kw - 1;
        bool valid = (hP >= 0) && (hP < HH) && (wP >= 0) && (wP < WW);
        const ushort_t* brow = xtb + (size_t)(hP * WW + wP) * 320;
#pragma unroll 1
        for (int cs = 0; cs < 10; ++cs) {
            int ci0 = cs * 32;
            uint4 vb0 = make_uint4(0, 0, 0, 0), vb1 = make_uint4(0, 0, 0, 0);
            if (valid) {
                const uint4* gp = reinterpret_cast<const uint4*>(brow + ci0 + half * 16);
                vb0 = gp[0];
                vb1 = gp[1];
            }
            uint4 va0, va1;
            if (t < 160) {
                const uint4* ga = reinterpret_cast<const uint4*>(
                    wmf + ((size_t)tap * 80 + r2) * 320 + ci0 + half * 16);
                va0 = ga[0];
                va1 = ga[1];
            }
            __syncthreads();
            {
                uint4* bp = reinterpret_cast<uint4*>(&b_lds[r2][half * 16]);
                bp[0] = vb0;
                bp[1] = vb1;
                if (t < 160) {
                    uint4* ap = reinterpret_cast<uint4*>(&a_lds[r2][half * 16]);
                    ap[0] = va0;
                    ap[1] = va1;
                }
            }
            __syncthreads();
            short8 af[5], bf[2];
#pragma unroll
            for (int m = 0; m < 5; ++m)
                af[m] = *reinterpret_cast<const short8*>(&a_lds[m * 16 + l15][kq * 8]);
#pragma unroll
            for (int n = 0; n < 2; ++n)
                bf[n] = *reinterpret_cast<const short8*>(&b_lds[wid * 32 + n * 16 + l15][kq * 8]);
#pragma unroll
            for (int m = 0; m < 5; ++m)
#pragma unroll
                for (int n = 0; n < 2; ++n)
                    acc[m][n] = __builtin_amdgcn_mfma_f32_16x16x32_bf16(af[m], bf[n],
                                                                        acc[m][n], 0, 0, 0);
        }
    }
    float* ob = off + (size_t)z * 72 * HW + n0 + wid * 32;
#pragma unroll
    for (int m = 0; m < 5; ++m)
#pragma unroll
        for (int n = 0; n < 2; ++n)
#pragma unroll
            for (int e = 0; e < 4; ++e) {
                int o_l = m * 16 + kq * 4 + e;
                if (o_l < 72) ob[(size_t)o_l * HW + n * 16 + l15] = acc[m][n][e];
            }
}

// ---------------- deformable conv via MFMA bf16 (r10 phases + double-buffered LDS) ----------------
// r10 geometry verbatim: grid 768 XCD-chunked, block (z,h), 4 waves x (64o x 64w),
// 4x4 frags, XT sampling, same epilogue. ONLY change: b_lds[2][...] double buffer;
// sample tap k+1 and MFMA tap k share one barrier interval (one sync per tap), so
// sample loads overlap MFMA across (and within) waves.
__global__ void __launch_bounds__(256, 2) deform_mfma(const ushort_t* __restrict__ XT,
                                                      const float* __restrict__ off,
                                                      const ushort_t* __restrict__ wmf,
                                                      ushort_t* __restrict__ FT) {
    __shared__ ushort_t b_lds[2][64][264];   // 67,584 B
    int u = blockIdx.x & 7, v = blockIdx.x >> 3;
    int lin = u * 96 + v;
    int z = lin >> 6, h = lin & 63;
    int b = z & 3, pair = z >> 2;

    const ushort_t* xtz = XT + (size_t)z * HW * 320;
    const float* offp = off + (size_t)z * 72 * HW;
    int tid = threadIdx.x;
    int lane = tid & 63;
    int g = tid >> 6;
    int l15 = tid & 15;
    int kq = (tid >> 4) & 3;

    f32x4 acc[4][4];
#pragma unroll
    for (int m = 0; m < 4; ++m)
#pragma unroll
        for (int n = 0; n < 4; ++n) acc[m][n] = (f32x4){0.f, 0.f, 0.f, 0.f};

    auto sample_tap = [&](int k, int bsel) {
        float oy = offp[(size_t)(g * 18 + k * 2 + 0) * HW + h * WW + lane];
        float ox = offp[(size_t)(g * 18 + k * 2 + 1) * HW + h * WW + lane];
        float py = (float)h + (float)(k / 3 - 1) + oy;
        float px = (float)lane + (float)(k % 3 - 1) + ox;
        float y0f = floorf(py), x0f = floorf(px);
        float fy = py - y0f, fx = px - x0f;
        int y0 = (int)y0f, x0 = (int)x0f;
        int y1 = y0 + 1, x1 = x0 + 1;
        bool vy0 = (y0 >= 0) && (y0 < HH);
        bool vy1 = (y1 >= 0) && (y1 < HH);
        bool vx0 = (x0 >= 0) && (x0 < WW);
        bool vx1 = (x1 >= 0) && (x1 < WW);
        float w00 = (1.f - fy) * (1.f - fx) * ((vy0 && vx0) ? 1.f : 0.f);
        float w01 = (1.f - fy) * fx * ((vy0 && vx1) ? 1.f : 0.f);
        float w10 = fy * (1.f - fx) * ((vy1 && vx0) ? 1.f : 0.f);
        float w11 = fy * fx * ((vy1 && vx1) ? 1.f : 0.f);
        int cy0 = min(max(y0, 0), HH - 1), cy1 = min(max(y1, 0), HH - 1);
        int cx0 = min(max(x0, 0), WW - 1), cx1 = min(max(x1, 0), WW - 1);
        const ushort_t* p00 = xtz + (size_t)(cy0 * WW + cx0) * 320 + g * 64;
        const ushort_t* p01 = xtz + (size_t)(cy0 * WW + cx1) * 320 + g * 64;
        const ushort_t* p10 = xtz + (size_t)(cy1 * WW + cx0) * 320 + g * 64;
        const ushort_t* p11 = xtz + (size_t)(cy1 * WW + cx1) * 320 + g * 64;
#pragma unroll
        for (int c0 = 0; c0 < 64; c0 += 8) {
            uint4 a00 = *reinterpret_cast<const uint4*>(p00 + c0);
            uint4 a01 = *reinterpret_cast<const uint4*>(p01 + c0);
            uint4 a10 = *reinterpret_cast<const uint4*>(p10 + c0);
            uint4 a11 = *reinterpret_cast<const uint4*>(p11 + c0);
            unsigned pw[4];
            const unsigned* u00 = &a00.x;
            const unsigned* u01 = &a01.x;
            const unsigned* u10 = &a10.x;
            const unsigned* u11 = &a11.x;
#pragma unroll
            for (int qq = 0; qq < 4; ++qq) {
                float s0 = w00 * bflo(u00[qq]) + w01 * bflo(u01[qq]) +
                           w10 * bflo(u10[qq]) + w11 * bflo(u11[qq]);
                float s1 = w00 * bfhi(u00[qq]) + w01 * bfhi(u01[qq]) +
                           w10 * bfhi(u10[qq]) + w11 * bfhi(u11[qq]);
                pw[qq] = (unsigned)f2bf(s0) | ((unsigned)f2bf(s1) << 16);
            }
            *reinterpret_cast<uint4*>(&b_lds[bsel][lane][g * 64 + c0]) =
                make_uint4(pw[0], pw[1], pw[2], pw[3]);
        }
    };

    sample_tap(0, 0);
    __syncthreads();
    for (int k = 0; k < 9; ++k) {
        if (k < 8) sample_tap(k + 1, (k + 1) & 1);  // other buffer; overlaps MFMA below
        const ushort_t* wkbase = wmf + (size_t)k * 65536 + (size_t)(g * 64) * 256;
        int bsel = k & 1;
#pragma unroll 1
        for (int cs = 0; cs < 8; ++cs) {
            int c0 = cs * 32;
            short8 bfr[4], afr[4];
#pragma unroll
            for (int n = 0; n < 4; ++n)
                bfr[n] = *reinterpret_cast<const short8*>(
                    &b_lds[bsel][n * 16 + l15][c0 + kq * 8]);
#pragma unroll
            for (int m = 0; m < 4; ++m)
                afr[m] = *reinterpret_cast<const short8*>(
                    wkbase + (size_t)(m * 16 + l15) * 256 + c0 + kq * 8);
#pragma unroll
            for (int m = 0; m < 4; ++m)
#pragma unroll
                for (int n = 0; n < 4; ++n)
                    acc[m][n] = __builtin_amdgcn_mfma_f32_16x16x32_bf16(afr[m], bfr[n],
                                                                        acc[m][n], 0, 0, 0);
        }
        __syncthreads();
    }
    // ---- epilogue (r10 verbatim, into buffer 0) ----
#pragma unroll
    for (int m = 0; m < 4; ++m)
#pragma unroll
        for (int n = 0; n < 4; ++n) {
            unsigned lo = (unsigned)f2bf(acc[m][n][0]) | ((unsigned)f2bf(acc[m][n][1]) << 16);
            unsigned hi = (unsigned)f2bf(acc[m][n][2]) | ((unsigned)f2bf(acc[m][n][3]) << 16);
            uint2 vv = make_uint2(lo, hi);
            *reinterpret_cast<uint2*>(&b_lds[0][n * 16 + l15][g * 64 + m * 16 + kq * 4]) = vv;
        }
    __syncthreads();
    int wout = tid >> 2, ch = tid & 3;
    ushort_t* dst = FT + ((size_t)b * HW + h * 64 + wout) * 1024 + pair * 256 + ch * 64;
    const ushort_t* srcl = &b_lds[0][wout][ch * 64];
#pragma unroll
    for (int i = 0; i < 8; ++i) {
        uint4 vv = *reinterpret_cast<const uint4*>(srcl + i * 8);
        *reinterpret_cast<uint4*>(dst + i * 8) = vv;
    }
}

// ---------------- FT build (y part) ----------------
__global__ void __launch_bounds__(256) ft_build_y(const float* __restrict__ in,
                                                  ushort_t* __restrict__ FT) {
    __shared__ ushort_t tileT[64][72];
    int hw0 = blockIdx.x * 64;
    int ct = blockIdx.y;
    int b = blockIdx.z;
    int t = threadIdx.x;
    int cil = t >> 2, q = t & 3;
    const float* sp = in + ((size_t)(b * 4 + 3) * 256 + ct * 64 + cil) * HW + hw0 + q * 16;
#pragma unroll
    for (int i = 0; i < 16; ++i) tileT[q * 16 + i][cil] = f2bf(sp[i]);
    __syncthreads();
    int hwl = t >> 2;
    const uint4* tp = reinterpret_cast<const uint4*>(&tileT[hwl][q * 16]);
    uint4* op = reinterpret_cast<uint4*>(
        &FT[((size_t)b * HW + hw0 + hwl) * 1024 + 768 + ct * 64 + q * 16]);
    op[0] = tp[0];
    op[1] = tp[1];
}

// ---------------- fusion conv via MFMA bf16 (halo-staged B, XCD-chunked) ----------------
__global__ void __launch_bounds__(256, 2) fusion_mfma(const ushort_t* __restrict__ FT,
                                                      const ushort_t* __restrict__ wmf,
                                                      float* __restrict__ out) {
    __shared__ ushort_t a_lds[9][64][32];
    __shared__ ushort_t b_hal[264][32];
    int lin = ((blockIdx.x & 7) << 6) | (blockIdx.x >> 3);
    int ot = lin & 3;
    int g2 = lin >> 2;
    int n0t = g2 & 31;
    int b = g2 >> 5;
    int o0 = ot * 64;
    int h0 = n0t * 2;
    int t = threadIdx.x;
    int wid = t >> 6;
    int lane = t & 63;
    int l15 = lane & 15;
    int kq = lane >> 4;
    const ushort_t* ftb = FT + (size_t)b * HW * 1024;

    f32x4 acc[4][2];
#pragma unroll
    for (int fm = 0; fm < 4; ++fm)
#pragma unroll
        for (int fn = 0; fn < 2; ++fn) acc[fm][fn] = (f32x4){0.f, 0.f, 0.f, 0.f};

#pragma unroll 1
    for (int cs = 0; cs < 32; ++cs) {
        int ci0 = cs * 32;
        __syncthreads();
        for (int idx = t; idx < 264; idx += 256) {
            int r = idx / 66, c = idx - r * 66;
            int hP = h0 + r - 1, wP = c - 1;
            uint4* dst = reinterpret_cast<uint4*>(&b_hal[idx][0]);
            if (hP >= 0 && hP < HH && wP >= 0 && wP < WW) {
                const uint4* src = reinterpret_cast<const uint4*>(
                    ftb + (size_t)(hP * WW + wP) * 1024 + ci0);
                dst[0] = src[0];
                dst[1] = src[1];
                dst[2] = src[2];
                dst[3] = src[3];
            } else {
                uint4 zz = make_uint4(0, 0, 0, 0);
                dst[0] = zz;
                dst[1] = zz;
                dst[2] = zz;
                dst[3] = zz;
            }
        }
        for (int idx = t; idx < 2304; idx += 256) {
            int tp = idx >> 8;
            int rem = idx & 255;
            int o = rem >> 2, q = rem & 3;
            *reinterpret_cast<uint4*>(&a_lds[tp][o][q * 8]) =
                *reinterpret_cast<const uint4*>(
                    wmf + ((size_t)(tp * 256 + o0 + o) << 10) + ci0 + q * 8);
        }
        __syncthreads();
#pragma unroll 1
        for (int tap = 0; tap < 9; ++tap) {
            int kh = tap / 3, kw = tap - kh * 3;
            short8 af[4], bf[2];
#pragma unroll
            for (int m = 0; m < 4; ++m)
                af[m] = *reinterpret_cast<const short8*>(&a_lds[tap][m * 16 + l15][kq * 8]);
#pragma unroll
            for (int n = 0; n < 2; ++n) {
                int p = wid * 32 + n * 16 + l15;
                int pos = ((p >> 6) + kh) * 66 + (p & 63) + kw;
                bf[n] = *reinterpret_cast<const short8*>(&b_hal[pos][kq * 8]);
            }
#pragma unroll
            for (int m = 0; m < 4; ++m)
#pragma unroll
                for (int n = 0; n < 2; ++n)
                    acc[m][n] = __builtin_amdgcn_mfma_f32_16x16x32_bf16(af[m], bf[n],
                                                                        acc[m][n], 0, 0, 0);
        }
    }
    float* ob = out + ((size_t)b * 256 + o0) * HW + h0 * 64 + wid * 32;
#pragma unroll
    for (int fm = 0; fm < 4; ++fm)
#pragma unroll
        for (int fn = 0; fn < 2; ++fn)
#pragma unroll
            for (int e = 0; e < 4; ++e) {
                int o_l = fm * 16 + 4 * kq + e;
                ob[(size_t)o_l * HW + fn * 16 + l15] = acc[fm][fn][e];
            }
}

extern "C" void kernel_launch(void* const* d_in, const int* in_sizes, int n_in,
                              void* d_out, int out_size, void* d_ws, size_t ws_size,
                              hipStream_t stream) {
    const float* in   = (const float*)d_in[0];   // [16,256,64,64]
    const float* wOff = (const float*)d_in[1];   // [72,305,3,3]
    const float* wDef = (const float*)d_in[2];   // [256,256,3,3]
    const float* wFus = (const float*)d_in[3];   // [256,1024,3,3]
    float* out = (float*)d_out;                  // [4,256,64,64]
    char* base = (char*)d_ws;

    ushort_t* XT     = (ushort_t*)base;                 // 31,457,280 B
    ushort_t* FT     = (ushort_t*)(base + 31457280);    // 33,554,432 B -> 65,011,712
    float* corrP     = (float*)(base + 31457280);       // 38,535,168 B (dead early)
    float* offB      = (float*)(base + 65011712);       // 14,155,776 B -> 79,167,488
    ushort_t* wdefMF = (ushort_t*)(base + 79167488);    //  1,179,648 B -> 80,347,136
    ushort_t* woffMF = (ushort_t*)(base + 80347136);    //    460,800 B -> 80,807,936
    ushort_t* wfusMF = (ushort_t*)(base + 80807936);    //  4,718,592 B -> 85,526,528

    hipLaunchKernelGGL(prep_wdef, dim3((9 * 256 * 256 + 255) / 256), dim3(256), 0, stream,
                       wDef, wdefMF);
    hipLaunchKernelGGL(prep_woff, dim3((9 * 80 * 320 + 255) / 256), dim3(256), 0, stream,
                       wOff, woffMF);
    hipLaunchKernelGGL(prep_wfus, dim3((9 * 256 * 1024 + 255) / 256), dim3(256), 0, stream,
                       wFus, wfusMF);
    hipLaunchKernelGGL(xt_build, dim3(64, 4, 12), dim3(256), 0, stream, in, XT);
    hipLaunchKernelGGL(corr_partial, dim3(64, 12, 4), dim3(256), 0, stream, in, corrP);
    hipLaunchKernelGGL(corr_reduce, dim3(64, 12), dim3(256), 0, stream, corrP, XT);
    hipLaunchKernelGGL(offconv_mfma, dim3(32, 12), dim3(256), 0, stream, XT, woffMF, offB);
    hipLaunchKernelGGL(ft_build_y, dim3(64, 4, 4), dim3(256), 0, stream, in, FT);
    hipLaunchKernelGGL(deform_mfma, dim3(768), dim3(256), 0, stream, XT, offB, wdefMF, FT);
    hipLaunchKernelGGL(fusion_mfma, dim3(512), dim3(256), 0, stream, FT, wfusMF, out);
}

// Round 14
// 582.509 us; speedup vs baseline: 1.3964x; 1.0262x over previous
//
#include <hip/hip_runtime.h>

#define HH 64
#define WW 64
#define HW 4096
#define CC 256
#define BB 4
#define GG 4
#define NPAIR 3

typedef __attribute__((ext_vector_type(8))) short short8;
typedef __attribute__((ext_vector_type(4))) float f32x4;
typedef unsigned short ushort_t;

__device__ inline ushort_t f2bf(float x) {
    unsigned int u = __float_as_uint(x);
    unsigned int r = (u + 0x7fffu + ((u >> 16) & 1u)) >> 16;
    return (ushort_t)r;
}
__device__ inline float bflo(unsigned u) { return __uint_as_float(u << 16); }
__device__ inline float bfhi(unsigned u) { return __uint_as_float(u & 0xffff0000u); }

// ---------------- weight preps ----------------
__global__ void prep_wdef(const float* __restrict__ wd, ushort_t* __restrict__ wmf) {
    int idx = blockIdx.x * 256 + threadIdx.x;  // 9*256*256
    if (idx >= 9 * 256 * 256) return;
    int k = idx >> 16;
    int rem = idx & 65535;
    int o = rem >> 8;
    int c = rem & 255;
    wmf[idx] = f2bf(wd[((size_t)(o * 256 + c)) * 9 + k]);
}

__global__ void prep_woff(const float* __restrict__ wo, ushort_t* __restrict__ wmf) {
    int idx = blockIdx.x * 256 + threadIdx.x;  // 9*80*320
    if (idx >= 9 * 80 * 320) return;
    int k = idx / (80 * 320);
    int rem = idx % (80 * 320);
    int o = rem / 320;
    int ci = rem % 320;
    wmf[idx] = (o < 72 && ci < 305) ? f2bf(wo[((size_t)o * 305 + ci) * 9 + k]) : (ushort_t)0;
}

__global__ void prep_wfus(const float* __restrict__ wf, ushort_t* __restrict__ wmf) {
    int idx = blockIdx.x * 256 + threadIdx.x;  // 9*256*1024
    if (idx >= 9 * 256 * 1024) return;
    int k = idx / (256 * 1024);
    int rem = idx % (256 * 1024);
    int o = rem / 1024;
    int ci = rem % 1024;
    wmf[idx] = f2bf(wf[((size_t)o * 1024 + ci) * 9 + k]);
}

// ---------------- XT build ----------------
__global__ void __launch_bounds__(256) xt_build(const float* __restrict__ in,
                                                ushort_t* __restrict__ XT) {
    __shared__ ushort_t tileT[64][72];
    int hw0 = blockIdx.x * 64;
    int ct = blockIdx.y;
    int z = blockIdx.z;
    int pair = z >> 2, b = z & 3;
    int t = threadIdx.x;
    int cil = t >> 2, q = t & 3;
    const float* sp = in + ((size_t)(b * 4 + pair) * 256 + ct * 64 + cil) * HW + hw0 + q * 16;
#pragma unroll
    for (int i = 0; i < 16; ++i) tileT[q * 16 + i][cil] = f2bf(sp[i]);
    __syncthreads();
    int hwl = t >> 2;
    const uint4* tp = reinterpret_cast<const uint4*>(&tileT[hwl][q * 16]);
    uint4* op = reinterpret_cast<uint4*>(
        &XT[((size_t)z * HW + hw0 + hwl) * 320 + ct * 64 + q * 16]);
    op[0] = tp[0];
    op[1] = tp[1];
}

// ---------------- correlation partials ----------------
__global__ void __launch_bounds__(256, 8) corr_partial(const float* __restrict__ in,
                                                       float* __restrict__ P) {
    __shared__ float x1l[8][64];
    __shared__ float x2l[8][7][76];
    int h = blockIdx.x, z = blockIdx.y, cg = blockIdx.z;
    int pair = z >> 2, b = z & 3;
    const float* x1 = in + (size_t)(b * GG + pair) * CC * HW + h * WW;
    const float* x2 = in + (size_t)(b * GG + 3) * CC * HW;
    int tid = threadIdx.x;
    int w = tid & 63;
    int dg = tid >> 6;

    float acc[2][7];
#pragma unroll
    for (int i = 0; i < 2; ++i)
#pragma unroll
        for (int j = 0; j < 7; ++j) acc[i][j] = 0.f;

    for (int c0 = cg * 64; c0 < cg * 64 + 64; c0 += 8) {
        __syncthreads();
#pragma unroll
        for (int idx = tid; idx < 512; idx += 256) {
            int cc = idx >> 6, ww = idx & 63;
            x1l[cc][ww] = x1[(size_t)(c0 + cc) * HW + ww];
        }
        for (int idx = tid; idx < 8 * 7 * 76; idx += 256) {
            int cc = idx / 532;
            int rem = idx - cc * 532;
            int r = rem / 76;
            int cl = rem - r * 76;
            int row = h + 2 * (r - 3);
            int col = cl - 6;
            float v = 0.f;
            if (row >= 0 && row < HH && col >= 0 && col < WW)
                v = x2[(size_t)(c0 + cc) * HW + row * WW + col];
            x2l[cc][r][cl] = v;
        }
        __syncthreads();
#pragma unroll
        for (int cc = 0; cc < 8; ++cc) {
            float x1v = x1l[cc][w];
#pragma unroll
            for (int i = 0; i < 2; ++i) {
                int di = dg * 2 + i;
                if (di < 7) {
#pragma unroll
                    for (int dj = 0; dj < 7; ++dj)
                        acc[i][dj] += x1v * x2l[cc][di][w + 2 * dj];
                }
            }
        }
    }
    float* pp = P + ((size_t)(cg * 12 + z) * 49) * HW + h * WW + w;
#pragma unroll
    for (int i = 0; i < 2; ++i) {
        int di = dg * 2 + i;
        if (di < 7) {
#pragma unroll
            for (int dj = 0; dj < 7; ++dj)
                pp[(size_t)(di * 7 + dj) * HW] = acc[i][dj];
        }
    }
}

// ---------------- corr reduce ----------------
__global__ void __launch_bounds__(256) corr_reduce(const float* __restrict__ P,
                                                   ushort_t* __restrict__ XT) {
    int h = blockIdx.x, z = blockIdx.y;
    int tid = threadIdx.x;
    int w = tid & 63;
    int dg = tid >> 6;
    const size_t cgs = (size_t)12 * 49 * HW;
    ushort_t* xrow = XT + ((size_t)z * HW + h * WW + w) * 320;
#pragma unroll
    for (int i = 0; i < 2; ++i) {
        int di = dg * 2 + i;
        if (di < 7) {
#pragma unroll
            for (int dj = 0; dj < 7; ++dj) {
                int d = di * 7 + dj;
                const float* pp = P + ((size_t)z * 49 + d) * HW + h * WW + w;
                float s = pp[0] + pp[cgs] + pp[2 * cgs] + pp[3 * cgs];
                xrow[256 + d] = f2bf(s * (1.f / 256.f));
            }
        }
    }
    if (dg == 3) {
#pragma unroll
        for (int p = 0; p < 15; ++p) xrow[305 + p] = 0;
    }
}

// ---------------- offset conv via MFMA bf16 (halo-staged B, z-local XCD grid) ----------------
// 1-D grid 384 = 8 XCD x 48; lin = u*48+v -> z = lin/32, n0t = lin%32 (48 consecutive
// blocks share a z -> XT z-slice L2-resident per XCD). Per ci-chunk (10 x 32):
// stage B halo once (264 pos x 32 ci) + A for all 9 taps; taps read shifted LDS pos.
__global__ void __launch_bounds__(256, 2) offconv_mfma(const ushort_t* __restrict__ XT,
                                                       const ushort_t* __restrict__ wmf,
                                                       float* __restrict__ off) {
    __shared__ ushort_t a_lds[9][80][40];   // 57,600 B
    __shared__ ushort_t b_hal[264][40];     // 21,120 B
    int lin = (blockIdx.x & 7) * 48 + (blockIdx.x >> 3);
    int z = lin >> 5;
    int n0t = lin & 31;
    int h0 = n0t * 2;
    int t = threadIdx.x;
    int wid = t >> 6;
    int lane = t & 63;
    int l15 = lane & 15;
    int kq = lane >> 4;
    const ushort_t* xtb = XT + (size_t)z * HW * 320;

    f32x4 acc[5][2];
#pragma unroll
    for (int m = 0; m < 5; ++m)
#pragma unroll
        for (int n = 0; n < 2; ++n) acc[m][n] = (f32x4){0.f, 0.f, 0.f, 0.f};

#pragma unroll 1
    for (int cs = 0; cs < 10; ++cs) {
        int ci0 = cs * 32;
        __syncthreads();
        // stage B halo: 264 positions x 32 ci
        for (int idx = t; idx < 264; idx += 256) {
            int r = idx / 66, c = idx - r * 66;
            int hP = h0 + r - 1, wP = c - 1;
            uint4* dst = reinterpret_cast<uint4*>(&b_hal[idx][0]);
            if (hP >= 0 && hP < HH && wP >= 0 && wP < WW) {
                const uint4* src = reinterpret_cast<const uint4*>(
                    xtb + (size_t)(hP * WW + wP) * 320 + ci0);
                dst[0] = src[0];
                dst[1] = src[1];
                dst[2] = src[2];
                dst[3] = src[3];
            } else {
                uint4 zz = make_uint4(0, 0, 0, 0);
                dst[0] = zz;
                dst[1] = zz;
                dst[2] = zz;
                dst[3] = zz;
            }
        }
        // stage A: 9 taps x 80 o x 32 ci
        for (int idx = t; idx < 2880; idx += 256) {
            int tp = idx / 320;
            int rem = idx - tp * 320;
            int o = rem >> 2, q = rem & 3;
            *reinterpret_cast<uint4*>(&a_lds[tp][o][q * 8]) =
                *reinterpret_cast<const uint4*>(
                    wmf + ((size_t)tp * 80 + o) * 320 + ci0 + q * 8);
        }
        __syncthreads();
#pragma unroll 1
        for (int tap = 0; tap < 9; ++tap) {
            int kh = tap / 3, kw = tap - kh * 3;
            short8 af[5], bf[2];
#pragma unroll
            for (int m = 0; m < 5; ++m)
                af[m] = *reinterpret_cast<const short8*>(&a_lds[tap][m * 16 + l15][kq * 8]);
#pragma unroll
            for (int n = 0; n < 2; ++n) {
                int p = wid * 32 + n * 16 + l15;  // local hw 0..127
                int pos = ((p >> 6) + kh) * 66 + (p & 63) + kw;
                bf[n] = *reinterpret_cast<const short8*>(&b_hal[pos][kq * 8]);
            }
#pragma unroll
            for (int m = 0; m < 5; ++m)
#pragma unroll
                for (int n = 0; n < 2; ++n)
                    acc[m][n] = __builtin_amdgcn_mfma_f32_16x16x32_bf16(af[m], bf[n],
                                                                        acc[m][n], 0, 0, 0);
        }
    }
    float* ob = off + (size_t)z * 72 * HW + h0 * 64 + wid * 32;
#pragma unroll
    for (int m = 0; m < 5; ++m)
#pragma unroll
        for (int n = 0; n < 2; ++n)
#pragma unroll
            for (int e = 0; e < 4; ++e) {
                int o_l = m * 16 + kq * 4 + e;
                if (o_l < 72) ob[(size_t)o_l * HW + n * 16 + l15] = acc[m][n][e];
            }
}

// ---------------- deformable conv via MFMA bf16 (r10 optimum, verbatim) ----------------
__global__ void __launch_bounds__(256, 3) deform_mfma(const ushort_t* __restrict__ XT,
                                                      const float* __restrict__ off,
                                                      const ushort_t* __restrict__ wmf,
                                                      ushort_t* __restrict__ FT) {
    __shared__ ushort_t b_lds[64][264];
    int u = blockIdx.x & 7, v = blockIdx.x >> 3;
    int lin = u * 96 + v;
    int z = lin >> 6, h = lin & 63;
    int b = z & 3, pair = z >> 2;

    const ushort_t* xtz = XT + (size_t)z * HW * 320;
    const float* offp = off + (size_t)z * 72 * HW;
    int tid = threadIdx.x;
    int lane = tid & 63;
    int g = tid >> 6;
    int l15 = tid & 15;
    int kq = (tid >> 4) & 3;

    f32x4 acc[4][4];
#pragma unroll
    for (int m = 0; m < 4; ++m)
#pragma unroll
        for (int n = 0; n < 4; ++n) acc[m][n] = (f32x4){0.f, 0.f, 0.f, 0.f};

    for (int k = 0; k < 9; ++k) {
        __syncthreads();
        {
            float oy = offp[(size_t)(g * 18 + k * 2 + 0) * HW + h * WW + lane];
            float ox = offp[(size_t)(g * 18 + k * 2 + 1) * HW + h * WW + lane];
            float py = (float)h + (float)(k / 3 - 1) + oy;
            float px = (float)lane + (float)(k % 3 - 1) + ox;
            float y0f = floorf(py), x0f = floorf(px);
            float fy = py - y0f, fx = px - x0f;
            int y0 = (int)y0f, x0 = (int)x0f;
            int y1 = y0 + 1, x1 = x0 + 1;
            bool vy0 = (y0 >= 0) && (y0 < HH);
            bool vy1 = (y1 >= 0) && (y1 < HH);
            bool vx0 = (x0 >= 0) && (x0 < WW);
            bool vx1 = (x1 >= 0) && (x1 < WW);
            float w00 = (1.f - fy) * (1.f - fx) * ((vy0 && vx0) ? 1.f : 0.f);
            float w01 = (1.f - fy) * fx * ((vy0 && vx1) ? 1.f : 0.f);
            float w10 = fy * (1.f - fx) * ((vy1 && vx0) ? 1.f : 0.f);
            float w11 = fy * fx * ((vy1 && vx1) ? 1.f : 0.f);
            int cy0 = min(max(y0, 0), HH - 1), cy1 = min(max(y1, 0), HH - 1);
            int cx0 = min(max(x0, 0), WW - 1), cx1 = min(max(x1, 0), WW - 1);
            const ushort_t* p00 = xtz + (size_t)(cy0 * WW + cx0) * 320 + g * 64;
            const ushort_t* p01 = xtz + (size_t)(cy0 * WW + cx1) * 320 + g * 64;
            const ushort_t* p10 = xtz + (size_t)(cy1 * WW + cx0) * 320 + g * 64;
            const ushort_t* p11 = xtz + (size_t)(cy1 * WW + cx1) * 320 + g * 64;
#pragma unroll
            for (int c0 = 0; c0 < 64; c0 += 8) {
                uint4 a00 = *reinterpret_cast<const uint4*>(p00 + c0);
                uint4 a01 = *reinterpret_cast<const uint4*>(p01 + c0);
                uint4 a10 = *reinterpret_cast<const uint4*>(p10 + c0);
                uint4 a11 = *reinterpret_cast<const uint4*>(p11 + c0);
                unsigned pw[4];
                const unsigned* u00 = &a00.x;
                const unsigned* u01 = &a01.x;
                const unsigned* u10 = &a10.x;
                const unsigned* u11 = &a11.x;
#pragma unroll
                for (int q = 0; q < 4; ++q) {
                    float s0 = w00 * bflo(u00[q]) + w01 * bflo(u01[q]) +
                               w10 * bflo(u10[q]) + w11 * bflo(u11[q]);
                    float s1 = w00 * bfhi(u00[q]) + w01 * bfhi(u01[q]) +
                               w10 * bfhi(u10[q]) + w11 * bfhi(u11[q]);
                    pw[q] = (unsigned)f2bf(s0) | ((unsigned)f2bf(s1) << 16);
                }
                *reinterpret_cast<uint4*>(&b_lds[lane][g * 64 + c0]) =
                    make_uint4(pw[0], pw[1], pw[2], pw[3]);
            }
        }
        __syncthreads();
        const ushort_t* wkbase = wmf + (size_t)k * 65536 + (size_t)(g * 64) * 256;
#pragma unroll 1
        for (int cs = 0; cs < 8; ++cs) {
            int c0 = cs * 32;
            short8 bfr[4], afr[4];
#pragma unroll
            for (int n = 0; n < 4; ++n)
                bfr[n] = *reinterpret_cast<const short8*>(&b_lds[n * 16 + l15][c0 + kq * 8]);
#pragma unroll
            for (int m = 0; m < 4; ++m)
                afr[m] = *reinterpret_cast<const short8*>(
                    wkbase + (size_t)(m * 16 + l15) * 256 + c0 + kq * 8);
#pragma unroll
            for (int m = 0; m < 4; ++m)
#pragma unroll
                for (int n = 0; n < 4; ++n)
                    acc[m][n] = __builtin_amdgcn_mfma_f32_16x16x32_bf16(afr[m], bfr[n],
                                                                        acc[m][n], 0, 0, 0);
        }
    }
    __syncthreads();
#pragma unroll
    for (int m = 0; m < 4; ++m)
#pragma unroll
        for (int n = 0; n < 4; ++n) {
            unsigned lo = (unsigned)f2bf(acc[m][n][0]) | ((unsigned)f2bf(acc[m][n][1]) << 16);
            unsigned hi = (unsigned)f2bf(acc[m][n][2]) | ((unsigned)f2bf(acc[m][n][3]) << 16);
            uint2 vv = make_uint2(lo, hi);
            *reinterpret_cast<uint2*>(&b_lds[n * 16 + l15][g * 64 + m * 16 + kq * 4]) = vv;
        }
    __syncthreads();
    int wout = tid >> 2, ch = tid & 3;
    ushort_t* dst = FT + ((size_t)b * HW + h * 64 + wout) * 1024 + pair * 256 + ch * 64;
    const ushort_t* srcl = &b_lds[wout][ch * 64];
#pragma unroll
    for (int i = 0; i < 8; ++i) {
        uint4 vv = *reinterpret_cast<const uint4*>(srcl + i * 8);
        *reinterpret_cast<uint4*>(dst + i * 8) = vv;
    }
}

// ---------------- FT build (y part) ----------------
__global__ void __launch_bounds__(256) ft_build_y(const float* __restrict__ in,
                                                  ushort_t* __restrict__ FT) {
    __shared__ ushort_t tileT[64][72];
    int hw0 = blockIdx.x * 64;
    int ct = blockIdx.y;
    int b = blockIdx.z;
    int t = threadIdx.x;
    int cil = t >> 2, q = t & 3;
    const float* sp = in + ((size_t)(b * 4 + 3) * 256 + ct * 64 + cil) * HW + hw0 + q * 16;
#pragma unroll
    for (int i = 0; i < 16; ++i) tileT[q * 16 + i][cil] = f2bf(sp[i]);
    __syncthreads();
    int hwl = t >> 2;
    const uint4* tp = reinterpret_cast<const uint4*>(&tileT[hwl][q * 16]);
    uint4* op = reinterpret_cast<uint4*>(
        &FT[((size_t)b * HW + hw0 + hwl) * 1024 + 768 + ct * 64 + q * 16]);
    op[0] = tp[0];
    op[1] = tp[1];
}

// ---------------- fusion conv via MFMA bf16 (halo-staged, 80B LDS rows: bank-clean) ----------------
__global__ void __launch_bounds__(256, 2) fusion_mfma(const ushort_t* __restrict__ FT,
                                                      const ushort_t* __restrict__ wmf,
                                                      float* __restrict__ out) {
    __shared__ ushort_t a_lds[9][64][40];   // 46,080 B (80B rows -> ~2-way banks)
    __shared__ ushort_t b_hal[264][40];     // 21,120 B
    int lin = ((blockIdx.x & 7) << 6) | (blockIdx.x >> 3);
    int ot = lin & 3;
    int g2 = lin >> 2;
    int n0t = g2 & 31;
    int b = g2 >> 5;
    int o0 = ot * 64;
    int h0 = n0t * 2;
    int t = threadIdx.x;
    int wid = t >> 6;
    int lane = t & 63;
    int l15 = lane & 15;
    int kq = lane >> 4;
    const ushort_t* ftb = FT + (size_t)b * HW * 1024;

    f32x4 acc[4][2];
#pragma unroll
    for (int fm = 0; fm < 4; ++fm)
#pragma unroll
        for (int fn = 0; fn < 2; ++fn) acc[fm][fn] = (f32x4){0.f, 0.f, 0.f, 0.f};

#pragma unroll 1
    for (int cs = 0; cs < 32; ++cs) {
        int ci0 = cs * 32;
        __syncthreads();
        for (int idx = t; idx < 264; idx += 256) {
            int r = idx / 66, c = idx - r * 66;
            int hP = h0 + r - 1, wP = c - 1;
            uint4* dst = reinterpret_cast<uint4*>(&b_hal[idx][0]);
            if (hP >= 0 && hP < HH && wP >= 0 && wP < WW) {
                const uint4* src = reinterpret_cast<const uint4*>(
                    ftb + (size_t)(hP * WW + wP) * 1024 + ci0);
                dst[0] = src[0];
                dst[1] = src[1];
                dst[2] = src[2];
                dst[3] = src[3];
            } else {
                uint4 zz = make_uint4(0, 0, 0, 0);
                dst[0] = zz;
                dst[1] = zz;
                dst[2] = zz;
                dst[3] = zz;
            }
        }
        for (int idx = t; idx < 2304; idx += 256) {
            int tp = idx >> 8;
            int rem = idx & 255;
            int o = rem >> 2, q = rem & 3;
            *reinterpret_cast<uint4*>(&a_lds[tp][o][q * 8]) =
                *reinterpret_cast<const uint4*>(
                    wmf + ((size_t)(tp * 256 + o0 + o) << 10) + ci0 + q * 8);
        }
        __syncthreads();
#pragma unroll 1
        for (int tap = 0; tap < 9; ++tap) {
            int kh = tap / 3, kw = tap - kh * 3;
            short8 af[4], bf[2];
#pragma unroll
            for (int m = 0; m < 4; ++m)
                af[m] = *reinterpret_cast<const short8*>(&a_lds[tap][m * 16 + l15][kq * 8]);
#pragma unroll
            for (int n = 0; n < 2; ++n) {
                int p = wid * 32 + n * 16 + l15;
                int pos = ((p >> 6) + kh) * 66 + (p & 63) + kw;
                bf[n] = *reinterpret_cast<const short8*>(&b_hal[pos][kq * 8]);
            }
#pragma unroll
            for (int m = 0; m < 4; ++m)
#pragma unroll
                for (int n = 0; n < 2; ++n)
                    acc[m][n] = __builtin_amdgcn_mfma_f32_16x16x32_bf16(af[m], bf[n],
                                                                        acc[m][n], 0, 0, 0);
        }
    }
    float* ob = out + ((size_t)b * 256 + o0) * HW + h0 * 64 + wid * 32;
#pragma unroll
    for (int fm = 0; fm < 4; ++fm)
#pragma unroll
        for (int fn = 0; fn < 2; ++fn)
#pragma unroll
            for (int e = 0; e < 4; ++e) {
                int o_l = fm * 16 + 4 * kq + e;
                ob[(size_t)o_l * HW + fn * 16 + l15] = acc[fm][fn][e];
            }
}

extern "C" void kernel_launch(void* const* d_in, const int* in_sizes, int n_in,
                              void* d_out, int out_size, void* d_ws, size_t ws_size,
                              hipStream_t stream) {
    const float* in   = (const float*)d_in[0];   // [16,256,64,64]
    const float* wOff = (const float*)d_in[1];   // [72,305,3,3]
    const float* wDef = (const float*)d_in[2];   // [256,256,3,3]
    const float* wFus = (const float*)d_in[3];   // [256,1024,3,3]
    float* out = (float*)d_out;                  // [4,256,64,64]
    char* base = (char*)d_ws;

    ushort_t* XT     = (ushort_t*)base;                 // 31,457,280 B
    ushort_t* FT     = (ushort_t*)(base + 31457280);    // 33,554,432 B -> 65,011,712
    float* corrP     = (float*)(base + 31457280);       // 38,535,168 B (dead early)
    float* offB      = (float*)(base + 65011712);       // 14,155,776 B -> 79,167,488
    ushort_t* wdefMF = (ushort_t*)(base + 79167488);    //  1,179,648 B -> 80,347,136
    ushort_t* woffMF = (ushort_t*)(base + 80347136);    //    460,800 B -> 80,807,936
    ushort_t* wfusMF = (ushort_t*)(base + 80807936);    //  4,718,592 B -> 85,526,528

    hipLaunchKernelGGL(prep_wdef, dim3((9 * 256 * 256 + 255) / 256), dim3(256), 0, stream,
                       wDef, wdefMF);
    hipLaunchKernelGGL(prep_woff, dim3((9 * 80 * 320 + 255) / 256), dim3(256), 0, stream,
                       wOff, woffMF);
    hipLaunchKernelGGL(prep_wfus, dim3((9 * 256 * 1024 + 255) / 256), dim3(256), 0, stream,
                       wFus, wfusMF);
    hipLaunchKernelGGL(xt_build, dim3(64, 4, 12), dim3(256), 0, stream, in, XT);
    hipLaunchKernelGGL(corr_partial, dim3(64, 12, 4), dim3(256), 0, stream, in, corrP);
    hipLaunchKernelGGL(corr_reduce, dim3(64, 12), dim3(256), 0, stream, corrP, XT);
    hipLaunchKernelGGL(offconv_mfma, dim3(384), dim3(256), 0, stream, XT, woffMF, offB);
    hipLaunchKernelGGL(ft_build_y, dim3(64, 4, 4), dim3(256), 0, stream, in, FT);
    hipLaunchKernelGGL(deform_mfma, dim3(768), dim3(256), 0, stream, XT, offB, wdefMF, FT);
    hipLaunchKernelGGL(fusion_mfma, dim3(512), dim3(256), 0, stream, FT, wfusMF, out);
}